// Round 6
// baseline (648.875 us; speedup 1.0000x reference)
//
#include <hip/hip_runtime.h>
#include <cstdint>

// ============================================================================
// CEM policy. Verified bit-exact (r5: absmax=0.0) with:
//   - buggy-gather table semantics (Is<64 indexes env axis -> 6x64x32 tables)
//   - JAX threefry2x32 PARTITIONABLE counter mode, 32-bit draw = o0^o1
//   - XLA uniform->erfinv pipeline (contract off, log1p select)
//   - sequential-k fma chains, bias-last (Tensile rounding model)
//
// r5 counters: k_main 451us, VGPR 44, VALU-saturated-ish, ~50% issue eff.
// Theory: W1aT s_load stream (16KB/qeval) thrashes scalar K$; all waves
// stall on the same lgkmcnt points.
// r6 change: E=2 env-batching in k_main -- each weight load feeds 2 fma
// chains (2 envs), halving SMEM traffic per FLOP and doubling ILP.
//
// ws layout (floats): S_pre 1048576 | W1aT 4096 | T 4*12288 | meanW 2048 |
//                     stdW 2048  => ~4.42 MB required.
// ============================================================================

#define TF_C 0x1BD11BDAu

__host__ __device__ __forceinline__ void tf20(uint32_t ks0, uint32_t ks1,
                                              uint32_t x0, uint32_t x1,
                                              uint32_t& o0, uint32_t& o1) {
  uint32_t ks2 = ks0 ^ ks1 ^ TF_C;
  x0 += ks0; x1 += ks1;
#define TF_RND(r) { x0 += x1; x1 = (x1 << (r)) | (x1 >> (32 - (r))); x1 ^= x0; }
  TF_RND(13) TF_RND(15) TF_RND(26) TF_RND(6)
  x0 += ks1; x1 += ks2 + 1u;
  TF_RND(17) TF_RND(29) TF_RND(16) TF_RND(24)
  x0 += ks2; x1 += ks0 + 2u;
  TF_RND(13) TF_RND(15) TF_RND(26) TF_RND(6)
  x0 += ks0; x1 += ks1 + 3u;
  TF_RND(17) TF_RND(29) TF_RND(16) TF_RND(24)
  x0 += ks1; x1 += ks2 + 4u;
  TF_RND(13) TF_RND(15) TF_RND(26) TF_RND(6)
  x0 += ks2; x1 += ks0 + 5u;
#undef TF_RND
  o0 = x0; o1 = x1;
}

// partitionable 32-bit draw for flat element index f (< 2^32 here, hi word 0)
__host__ __device__ __forceinline__ uint32_t pbits(uint32_t k0, uint32_t k1,
                                                   uint32_t f) {
  uint32_t o0, o1;
  tf20(k0, k1, 0u, f, o0, o1);
  return o0 ^ o1;
}

// bits -> N(0,1) sample, matching XLA bit-for-bit (verified r5).
__device__ __forceinline__ float eps_from_bits(uint32_t bits) {
#pragma clang fp contract(off)
  const float LO = __uint_as_float(0xbf7fffffu);  // nextafter(-1, 0)
  float f = __uint_as_float((bits >> 9) | 0x3f800000u) - 1.0f;  // [0,1)
  float u = fmaxf(LO, f * 2.0f + LO);
  float t = -(u * u);
  float w_large = logf(t + 1.0f);
  float w_small = ((-0.5f * t) + 1.0f) * t;
  float w = (fabsf(t) < 1e-4f) ? w_small : w_large;
  w = -w;
  float p;
  if (w < 5.0f) {
    float ww = w - 2.5f;
    p = 2.81022636e-08f;
    p = 3.43273939e-07f + p * ww;
    p = -3.5233877e-06f + p * ww;
    p = -4.39150654e-06f + p * ww;
    p = 0.00021858087f + p * ww;
    p = -0.00125372503f + p * ww;
    p = -0.00417768164f + p * ww;
    p = 0.246640727f + p * ww;
    p = 1.50140941f + p * ww;
  } else {
    float ww = sqrtf(w) - 3.0f;
    p = -0.000200214257f;
    p = 0.000100950558f + p * ww;
    p = 0.00134934322f + p * ww;
    p = -0.00367342844f + p * ww;
    p = 0.00573950773f + p * ww;
    p = -0.0076224613f + p * ww;
    p = 0.00943887047f + p * ww;
    p = 1.00167406f + p * ww;
    p = 2.83297682f + p * ww;
  }
  float r = p * u;
  return __uint_as_float(0x3fb504f3u) * r;  // float32(sqrt(2)) * erfinv(u)
}

// lane = candidate c. eps[k] = eps(c, env, k); f = c*2^18 + env*32 + k.
__device__ __forceinline__ void gen_eps(uint32_t k0, uint32_t k1, int env,
                                        int lane, float eps[32]) {
  const uint32_t base = (uint32_t)lane * 262144u + (uint32_t)env * 32u;
#pragma unroll
  for (int k = 0; k < 32; ++k)
    eps[k] = eps_from_bits(pbits(k0, k1, base + (uint32_t)k));
}

// single-env qeval (used by k_stage1 only)
__device__ __forceinline__ float qeval(const float* __restrict__ Srow,
                                       const float* __restrict__ W1aT,
                                       const float* __restrict__ b1,
                                       const float* __restrict__ W2,
                                       float b2v, const float a[32]) {
  float q = 0.0f;
#pragma unroll 4
  for (int j = 0; j < 128; ++j) {
    float h = Srow[j];
    const float* wr = W1aT + j * 32;
#pragma unroll
    for (int k = 0; k < 32; ++k) h = __builtin_fmaf(a[k], wr[k], h);
    h = h + b1[j];
    h = fmaxf(h, 0.0f);
    q = __builtin_fmaf(h, W2[j], q);
  }
  return q + b2v;
}

// dual-env qeval: each weight load feeds 2 independent fma chains.
__device__ __forceinline__ void qeval2(const float* __restrict__ SrowA,
                                       const float* __restrict__ SrowB,
                                       const float* __restrict__ W1aT,
                                       const float* __restrict__ b1,
                                       const float* __restrict__ W2,
                                       float b2v, const float aA[32],
                                       const float aB[32], float& qAo,
                                       float& qBo) {
  float qA = 0.0f, qB = 0.0f;
#pragma unroll 4
  for (int j = 0; j < 128; ++j) {
    float h0 = SrowA[j];
    float h1 = SrowB[j];
    const float* wr = W1aT + j * 32;
#pragma unroll
    for (int k = 0; k < 32; ++k) {
      float w = wr[k];
      h0 = __builtin_fmaf(aA[k], w, h0);
      h1 = __builtin_fmaf(aB[k], w, h1);
    }
    float bj = b1[j];
    h0 = fmaxf(h0 + bj, 0.0f);
    h1 = fmaxf(h1 + bj, 0.0f);
    float wj = W2[j];
    qA = __builtin_fmaf(h0, wj, qA);
    qB = __builtin_fmaf(h1, wj, qB);
  }
  qAo = qA + b2v;
  qBo = qB + b2v;
}

// iterative wave argmax: value desc, index asc (matches lax.top_k ordering).
__device__ __forceinline__ void top6(float q, int lane, int top[6]) {
  float qv = q;
#pragma unroll
  for (int i = 0; i < 6; ++i) {
    float v = qv;
    int idx = lane;
#pragma unroll
    for (int off = 1; off < 64; off <<= 1) {
      float ov = __shfl_xor(v, off, 64);
      int oi = __shfl_xor(idx, off, 64);
      if (ov > v || (ov == v && oi < idx)) { v = ov; idx = oi; }
    }
    top[i] = __builtin_amdgcn_readfirstlane(idx);
    if (lane == idx) qv = -__builtin_inff();
  }
}

// mean (div 6) and ddof=1 std (div 5), sequential order, no fma.
__device__ __forceinline__ void stats6(const float sel[6], float& mean, float& sd) {
#pragma clang fp contract(off)
  float s = ((((sel[0] + sel[1]) + sel[2]) + sel[3]) + sel[4]) + sel[5];
  mean = s / 6.0f;
  float d0 = sel[0] - mean, d1 = sel[1] - mean, d2 = sel[2] - mean;
  float d3 = sel[3] - mean, d4 = sel[4] - mean, d5 = sel[5] - mean;
  float p0 = d0 * d0, p1 = d1 * d1, p2 = d2 * d2;
  float p3 = d3 * d3, p4 = d4 * d4, p5 = d5 * d5;
  float ss = ((((p0 + p1) + p2) + p3) + p4) + p5;
  sd = sqrtf(ss / 5.0f);
}

__device__ __forceinline__ float rdlane(float v, int l) {
  return __int_as_float(__builtin_amdgcn_readlane(__float_as_int(v), l));
}

// ---------------------------------------------------------------------------
__global__ void __launch_bounds__(128) k_prep_spre(const float* __restrict__ state,
                                                   const float* __restrict__ W1,
                                                   float* __restrict__ S_pre) {
  const int b = blockIdx.x;   // 8192
  const int j = threadIdx.x;  // 128
  float h = 0.0f;             // bias added later, after the action part
  const float* srow = state + (size_t)b * 64;
#pragma unroll 8
  for (int k = 0; k < 64; ++k) h = __builtin_fmaf(srow[k], W1[k * 128 + j], h);
  S_pre[(size_t)b * 128 + j] = h;
}

__global__ void __launch_bounds__(256) k_prep_misc(const float* __restrict__ W1,
                                                   float* __restrict__ W1aT,
                                                   float* __restrict__ T0,
                                                   float* __restrict__ meanW,
                                                   float* __restrict__ stdW,
                                                   uint32_t K0, uint32_t K1) {
  const int tid = blockIdx.x * 256 + threadIdx.x;  // 12288 threads
  if (tid < 4096) {  // W1aT[j][k] = W1[64+k][j]
    int j = tid >> 5, k = tid & 31;
    W1aT[tid] = W1[(64 + k) * 128 + j];
  }
  {  // T0[i][e][k] = eps_0(i,e,k)  (mean=0, std=1 -> exact)
    int i = tid >> 11, rem = tid & 2047;  // rem = e*32+k
    uint32_t f = (uint32_t)i * 262144u + (uint32_t)rem;
    T0[tid] = eps_from_bits(pbits(K0, K1, f));
  }
  if (tid < 2048) { meanW[tid] = 0.0f; stdW[tid] = 1.0f; }
}

// one CEM iteration for envs 0..63; produces T_{it+1}. grid 16 x 256.
__global__ void __launch_bounds__(256) k_stage1(const float* __restrict__ S_pre,
    const float* __restrict__ W1aT, const float* __restrict__ b1,
    const float* __restrict__ W2, const float* __restrict__ b2,
    const float* __restrict__ Tcur, float* __restrict__ Tnext,
    float* __restrict__ meanW, float* __restrict__ stdW, uint32_t K0,
    uint32_t K1, uint32_t NK0, uint32_t NK1) {
  const int lane = threadIdx.x & 63;
  const int e = __builtin_amdgcn_readfirstlane((int)(blockIdx.x * 4 + (threadIdx.x >> 6)));
  const int kk = lane & 31;
  float eps[32];
  gen_eps(K0, K1, e, lane, eps);
  float a[32];
  {
#pragma clang fp contract(off)
#pragma unroll
    for (int k = 0; k < 32; ++k) {
      float mk = meanW[e * 32 + k];
      float sk = stdW[e * 32 + k];
      a[k] = mk + sk * eps[k];
    }
  }
  float q = qeval(S_pre + (size_t)e * 128, W1aT, b1, W2, b2[0], a);
  int top[6];
  top6(q, lane, top);
  float sel[6];
#pragma unroll
  for (int i = 0; i < 6; ++i) sel[i] = Tcur[(size_t)((i * 64 + top[i]) * 32) + kk];
  float vmean, vsd;
  stats6(sel, vmean, vsd);
  if (lane < 32) {
    meanW[e * 32 + kk] = vmean;
    stdW[e * 32 + kk] = vsd;
  }
  // T_{it+1}[i][e][k] = mean_new[k] + std_new[k] * eps_{it+1}(i,e,k), i<6
#pragma unroll
  for (int t = 0; t < 3; ++t) {
    int m = lane * 3 + t;  // 0..191
    int i = m >> 5, k = m & 31;
    uint32_t f = (uint32_t)i * 262144u + (uint32_t)e * 32u + (uint32_t)k;
    float ev = eps_from_bits(pbits(NK0, NK1, f));
    float mk = __shfl(vmean, k, 64);
    float sk = __shfl(vsd, k, 64);
    float val;
    {
#pragma clang fp contract(off)
      val = mk + sk * ev;
    }
    Tnext[(size_t)((i * 64 + e) * 32 + k)] = val;
  }
}

// all 8192 envs, 4 fused iterations, E=2 envs per wave. grid 1024 x 256.
// Stats are lane-split: lanes 0..31 hold env A's per-k mean/std, lanes
// 32..63 hold env B's. a[] materialized via v_readlane (const lane idx).
__global__ void __launch_bounds__(256) k_main(const float* __restrict__ S_pre,
    const float* __restrict__ W1aT, const float* __restrict__ b1,
    const float* __restrict__ W2, const float* __restrict__ b2,
    const float* __restrict__ T, float* __restrict__ out, uint4 kx, uint4 ky) {
  const int lane = threadIdx.x & 63;
  const int g = __builtin_amdgcn_readfirstlane((int)(blockIdx.x * 4 + (threadIdx.x >> 6)));
  const int bA = 2 * g, bB = 2 * g + 1;
  const float* SrowA = S_pre + (size_t)bA * 128;
  const float* SrowB = S_pre + (size_t)bB * 128;
  const float bb2 = b2[0];
  const int kk = lane & 31;
  float vmean = 0.0f, vsd = 1.0f;  // lane-split stats (A: 0..31, B: 32..63)
  for (int it = 0; it < 4; ++it) {
    uint32_t K0 = it == 0 ? kx.x : it == 1 ? kx.y : it == 2 ? kx.z : kx.w;
    uint32_t K1 = it == 0 ? ky.x : it == 1 ? ky.y : it == 2 ? ky.z : ky.w;
    float aA[32], aB[32];
    gen_eps(K0, K1, bA, lane, aA);   // eps_A
    gen_eps(K0, K1, bB, lane, aB);   // eps_B
    if (it != 0) {
#pragma clang fp contract(off)
#pragma unroll
      for (int k = 0; k < 32; ++k) {
        float mkA = rdlane(vmean, k), skA = rdlane(vsd, k);
        float mkB = rdlane(vmean, 32 + k), skB = rdlane(vsd, 32 + k);
        aA[k] = mkA + skA * aA[k];
        aB[k] = mkB + skB * aB[k];
      }
    }  // it==0: a = 0 + 1*eps = eps bitwise.
    float qA, qB;
    qeval2(SrowA, SrowB, W1aT, b1, W2, bb2, aA, aB, qA, qB);
    int topA[6], topB[6];
    top6(qA, lane, topA);
    top6(qB, lane, topB);
    const float* Tt = T + it * 12288;
    // lane-split gathers: lanes<32 use topA (env A), lanes>=32 topB (env B)
    int t0 = lane < 32 ? topA[0] : topB[0];
    float sel0 = Tt[(size_t)(t0 * 32) + kk];
    if (it == 3) {
      int env = lane < 32 ? bA : bB;
      out[(size_t)env * 32 + kk] = sel0;
    } else {
      float sel[6];
      sel[0] = sel0;
#pragma unroll
      for (int i = 1; i < 6; ++i) {
        int ti = lane < 32 ? topA[i] : topB[i];
        sel[i] = Tt[(size_t)((i * 64 + ti) * 32) + kk];
      }
      stats6(sel, vmean, vsd);  // lane-split: A in 0..31, B in 32..63
    }
  }
}

// ---------------------------------------------------------------------------
extern "C" void kernel_launch(void* const* d_in, const int* in_sizes, int n_in,
                              void* d_out, int out_size, void* d_ws,
                              size_t ws_size, hipStream_t stream) {
  const float* state = (const float*)d_in[0];  // 8192*64
  const float* W1 = (const float*)d_in[1];     // 96*128
  const float* b1 = (const float*)d_in[2];     // 128
  const float* W2 = (const float*)d_in[3];     // 128
  const float* b2 = (const float*)d_in[4];     // 1
  float* out = (float*)d_out;                  // 8192*32

  float* ws = (float*)d_ws;
  float* S_pre = ws;                    // 1,048,576 floats
  float* W1aT = ws + 1048576;           // 4,096
  float* T = W1aT + 4096;               // 4 * 12,288
  float* meanW = T + 4 * 12288;         // 2,048
  float* stdW = meanW + 2048;           // 2,048  (total ~4.42 MB)

  // fold_in(key(42), it) = threefry cipher block (k=(0,42), x=(0,it))
  uint32_t K0[4], K1[4];
  for (uint32_t i = 0; i < 4; ++i) {
    uint32_t a, bb;
    tf20(0u, 42u, 0u, i, a, bb);
    K0[i] = a;
    K1[i] = bb;
  }

  k_prep_spre<<<8192, 128, 0, stream>>>(state, W1, S_pre);
  k_prep_misc<<<48, 256, 0, stream>>>(W1, W1aT, T, meanW, stdW, K0[0], K1[0]);
  for (int it = 0; it < 3; ++it)
    k_stage1<<<16, 256, 0, stream>>>(S_pre, W1aT, b1, W2, b2, T + it * 12288,
                                     T + (it + 1) * 12288, meanW, stdW, K0[it],
                                     K1[it], K0[it + 1], K1[it + 1]);
  k_main<<<1024, 256, 0, stream>>>(S_pre, W1aT, b1, W2, b2, T, out,
                                   make_uint4(K0[0], K0[1], K0[2], K0[3]),
                                   make_uint4(K1[0], K1[1], K1[2], K1[3]));
}

// Round 8
// 594.288 us; speedup vs baseline: 1.0919x; 1.0919x over previous
//
#include <hip/hip_runtime.h>
#include <cstdint>

// ============================================================================
// CEM policy. Verified bit-exact (r5: absmax=0.0) with:
//   - buggy-gather table semantics (Is<64 indexes env axis -> 6x64x32 tables)
//   - JAX threefry2x32 PARTITIONABLE counter mode, 32-bit draw = o0^o1
//   - XLA uniform->erfinv pipeline (contract off, log1p select)
//   - sequential-k fma chains, bias-last (Tensile rounding model)
//
// Perf history:
//   r5  E=1: 451us  VGPR 44  occ 45%  VALUBusy 112
//   r6  E=2: 513us  VGPR 80  occ 26%  -> REGRESSION: occupancy loss beat
//       ILP gain; kernel is latency-bound hidden by TLP, not K$-bound.
//   r7: (never ran -- GPU timeout) E=1 + j4-ILP in qeval: 4 independent
//       h-chains per wave (covers 4-cyc dependent-fma latency in-wave),
//       VGPR target <64, grid 2048 blocks (8192 waves). Resubmitted r8.
//
// ws layout (floats): S_pre 1048576 | W1aT 4096 | T 4*12288 | meanW 2048 |
//                     stdW 2048  => ~4.42 MB required.
// ============================================================================

#define TF_C 0x1BD11BDAu

__host__ __device__ __forceinline__ void tf20(uint32_t ks0, uint32_t ks1,
                                              uint32_t x0, uint32_t x1,
                                              uint32_t& o0, uint32_t& o1) {
  uint32_t ks2 = ks0 ^ ks1 ^ TF_C;
  x0 += ks0; x1 += ks1;
#define TF_RND(r) { x0 += x1; x1 = (x1 << (r)) | (x1 >> (32 - (r))); x1 ^= x0; }
  TF_RND(13) TF_RND(15) TF_RND(26) TF_RND(6)
  x0 += ks1; x1 += ks2 + 1u;
  TF_RND(17) TF_RND(29) TF_RND(16) TF_RND(24)
  x0 += ks2; x1 += ks0 + 2u;
  TF_RND(13) TF_RND(15) TF_RND(26) TF_RND(6)
  x0 += ks0; x1 += ks1 + 3u;
  TF_RND(17) TF_RND(29) TF_RND(16) TF_RND(24)
  x0 += ks1; x1 += ks2 + 4u;
  TF_RND(13) TF_RND(15) TF_RND(26) TF_RND(6)
  x0 += ks2; x1 += ks0 + 5u;
#undef TF_RND
  o0 = x0; o1 = x1;
}

// partitionable 32-bit draw for flat element index f (< 2^32 here, hi word 0)
__host__ __device__ __forceinline__ uint32_t pbits(uint32_t k0, uint32_t k1,
                                                   uint32_t f) {
  uint32_t o0, o1;
  tf20(k0, k1, 0u, f, o0, o1);
  return o0 ^ o1;
}

// bits -> N(0,1) sample, matching XLA bit-for-bit (verified r5).
__device__ __forceinline__ float eps_from_bits(uint32_t bits) {
#pragma clang fp contract(off)
  const float LO = __uint_as_float(0xbf7fffffu);  // nextafter(-1, 0)
  float f = __uint_as_float((bits >> 9) | 0x3f800000u) - 1.0f;  // [0,1)
  float u = fmaxf(LO, f * 2.0f + LO);
  float t = -(u * u);
  float w_large = logf(t + 1.0f);
  float w_small = ((-0.5f * t) + 1.0f) * t;
  float w = (fabsf(t) < 1e-4f) ? w_small : w_large;
  w = -w;
  float p;
  if (w < 5.0f) {
    float ww = w - 2.5f;
    p = 2.81022636e-08f;
    p = 3.43273939e-07f + p * ww;
    p = -3.5233877e-06f + p * ww;
    p = -4.39150654e-06f + p * ww;
    p = 0.00021858087f + p * ww;
    p = -0.00125372503f + p * ww;
    p = -0.00417768164f + p * ww;
    p = 0.246640727f + p * ww;
    p = 1.50140941f + p * ww;
  } else {
    float ww = sqrtf(w) - 3.0f;
    p = -0.000200214257f;
    p = 0.000100950558f + p * ww;
    p = 0.00134934322f + p * ww;
    p = -0.00367342844f + p * ww;
    p = 0.00573950773f + p * ww;
    p = -0.0076224613f + p * ww;
    p = 0.00943887047f + p * ww;
    p = 1.00167406f + p * ww;
    p = 2.83297682f + p * ww;
  }
  float r = p * u;
  return __uint_as_float(0x3fb504f3u) * r;  // float32(sqrt(2)) * erfinv(u)
}

// lane = candidate c. eps[k] = eps(c, env, k); f = c*2^18 + env*32 + k.
__device__ __forceinline__ void gen_eps(uint32_t k0, uint32_t k1, int env,
                                        int lane, float eps[32]) {
  const uint32_t base = (uint32_t)lane * 262144u + (uint32_t)env * 32u;
#pragma unroll
  for (int k = 0; k < 32; ++k)
    eps[k] = eps_from_bits(pbits(k0, k1, base + (uint32_t)k));
}

// Q(state_b, a) with j4-ILP: 4 independent h-chains (outputs j..j+3) share
// each a[k] read, covering dependent-fma latency in-wave. q accumulates
// sequentially j=0..127 (bit-exact order preserved).
__device__ __forceinline__ float qeval(const float* __restrict__ Srow,
                                       const float* __restrict__ W1aT,
                                       const float* __restrict__ b1,
                                       const float* __restrict__ W2,
                                       float b2v, const float a[32]) {
  float q = 0.0f;
#pragma unroll 2
  for (int j = 0; j < 128; j += 4) {
    float h0 = Srow[j + 0];
    float h1 = Srow[j + 1];
    float h2 = Srow[j + 2];
    float h3 = Srow[j + 3];
    const float* wr = W1aT + j * 32;
#pragma unroll
    for (int k = 0; k < 32; ++k) {
      float ak = a[k];
      h0 = __builtin_fmaf(ak, wr[k], h0);
      h1 = __builtin_fmaf(ak, wr[32 + k], h1);
      h2 = __builtin_fmaf(ak, wr[64 + k], h2);
      h3 = __builtin_fmaf(ak, wr[96 + k], h3);
    }
    h0 = fmaxf(h0 + b1[j + 0], 0.0f);
    h1 = fmaxf(h1 + b1[j + 1], 0.0f);
    h2 = fmaxf(h2 + b1[j + 2], 0.0f);
    h3 = fmaxf(h3 + b1[j + 3], 0.0f);
    q = __builtin_fmaf(h0, W2[j + 0], q);
    q = __builtin_fmaf(h1, W2[j + 1], q);
    q = __builtin_fmaf(h2, W2[j + 2], q);
    q = __builtin_fmaf(h3, W2[j + 3], q);
  }
  return q + b2v;
}

// iterative wave argmax: value desc, index asc (matches lax.top_k ordering).
__device__ __forceinline__ void top6(float q, int lane, int top[6]) {
  float qv = q;
#pragma unroll
  for (int i = 0; i < 6; ++i) {
    float v = qv;
    int idx = lane;
#pragma unroll
    for (int off = 1; off < 64; off <<= 1) {
      float ov = __shfl_xor(v, off, 64);
      int oi = __shfl_xor(idx, off, 64);
      if (ov > v || (ov == v && oi < idx)) { v = ov; idx = oi; }
    }
    top[i] = __builtin_amdgcn_readfirstlane(idx);
    if (lane == idx) qv = -__builtin_inff();
  }
}

// mean (div 6) and ddof=1 std (div 5), sequential order, no fma.
__device__ __forceinline__ void stats6(const float sel[6], float& mean, float& sd) {
#pragma clang fp contract(off)
  float s = ((((sel[0] + sel[1]) + sel[2]) + sel[3]) + sel[4]) + sel[5];
  mean = s / 6.0f;
  float d0 = sel[0] - mean, d1 = sel[1] - mean, d2 = sel[2] - mean;
  float d3 = sel[3] - mean, d4 = sel[4] - mean, d5 = sel[5] - mean;
  float p0 = d0 * d0, p1 = d1 * d1, p2 = d2 * d2;
  float p3 = d3 * d3, p4 = d4 * d4, p5 = d5 * d5;
  float ss = ((((p0 + p1) + p2) + p3) + p4) + p5;
  sd = sqrtf(ss / 5.0f);
}

__device__ __forceinline__ float rdlane(float v, int l) {
  return __int_as_float(__builtin_amdgcn_readlane(__float_as_int(v), l));
}

// ---------------------------------------------------------------------------
__global__ void __launch_bounds__(128) k_prep_spre(const float* __restrict__ state,
                                                   const float* __restrict__ W1,
                                                   float* __restrict__ S_pre) {
  const int b = blockIdx.x;   // 8192
  const int j = threadIdx.x;  // 128
  float h = 0.0f;             // bias added later, after the action part
  const float* srow = state + (size_t)b * 64;
#pragma unroll 8
  for (int k = 0; k < 64; ++k) h = __builtin_fmaf(srow[k], W1[k * 128 + j], h);
  S_pre[(size_t)b * 128 + j] = h;
}

__global__ void __launch_bounds__(256) k_prep_misc(const float* __restrict__ W1,
                                                   float* __restrict__ W1aT,
                                                   float* __restrict__ T0,
                                                   float* __restrict__ meanW,
                                                   float* __restrict__ stdW,
                                                   uint32_t K0, uint32_t K1) {
  const int tid = blockIdx.x * 256 + threadIdx.x;  // 12288 threads
  if (tid < 4096) {  // W1aT[j][k] = W1[64+k][j]
    int j = tid >> 5, k = tid & 31;
    W1aT[tid] = W1[(64 + k) * 128 + j];
  }
  {  // T0[i][e][k] = eps_0(i,e,k)  (mean=0, std=1 -> exact)
    int i = tid >> 11, rem = tid & 2047;  // rem = e*32+k
    uint32_t f = (uint32_t)i * 262144u + (uint32_t)rem;
    T0[tid] = eps_from_bits(pbits(K0, K1, f));
  }
  if (tid < 2048) { meanW[tid] = 0.0f; stdW[tid] = 1.0f; }
}

// one CEM iteration for envs 0..63; produces T_{it+1}. grid 16 x 256.
__global__ void __launch_bounds__(256) k_stage1(const float* __restrict__ S_pre,
    const float* __restrict__ W1aT, const float* __restrict__ b1,
    const float* __restrict__ W2, const float* __restrict__ b2,
    const float* __restrict__ Tcur, float* __restrict__ Tnext,
    float* __restrict__ meanW, float* __restrict__ stdW, uint32_t K0,
    uint32_t K1, uint32_t NK0, uint32_t NK1) {
  const int lane = threadIdx.x & 63;
  const int e = __builtin_amdgcn_readfirstlane((int)(blockIdx.x * 4 + (threadIdx.x >> 6)));
  const int kk = lane & 31;
  float eps[32];
  gen_eps(K0, K1, e, lane, eps);
  float a[32];
  {
#pragma clang fp contract(off)
#pragma unroll
    for (int k = 0; k < 32; ++k) {
      float mk = meanW[e * 32 + k];
      float sk = stdW[e * 32 + k];
      a[k] = mk + sk * eps[k];
    }
  }
  float q = qeval(S_pre + (size_t)e * 128, W1aT, b1, W2, b2[0], a);
  int top[6];
  top6(q, lane, top);
  float sel[6];
#pragma unroll
  for (int i = 0; i < 6; ++i) sel[i] = Tcur[(size_t)((i * 64 + top[i]) * 32) + kk];
  float vmean, vsd;
  stats6(sel, vmean, vsd);
  if (lane < 32) {
    meanW[e * 32 + kk] = vmean;
    stdW[e * 32 + kk] = vsd;
  }
  // T_{it+1}[i][e][k] = mean_new[k] + std_new[k] * eps_{it+1}(i,e,k), i<6
#pragma unroll
  for (int t = 0; t < 3; ++t) {
    int m = lane * 3 + t;  // 0..191
    int i = m >> 5, k = m & 31;
    uint32_t f = (uint32_t)i * 262144u + (uint32_t)e * 32u + (uint32_t)k;
    float ev = eps_from_bits(pbits(NK0, NK1, f));
    float mk = __shfl(vmean, k, 64);
    float sk = __shfl(vsd, k, 64);
    float val;
    {
#pragma clang fp contract(off)
      val = mk + sk * ev;
    }
    Tnext[(size_t)((i * 64 + e) * 32 + k)] = val;
  }
}

// all 8192 envs, 4 fused iterations, E=1 env per wave. grid 2048 x 256.
// mean/std live lane-sliced in 2 VGPRs; a[] materialized via v_readlane.
__global__ void __launch_bounds__(256) k_main(const float* __restrict__ S_pre,
    const float* __restrict__ W1aT, const float* __restrict__ b1,
    const float* __restrict__ W2, const float* __restrict__ b2,
    const float* __restrict__ T, float* __restrict__ out, uint4 kx, uint4 ky) {
  const int lane = threadIdx.x & 63;
  const int b = __builtin_amdgcn_readfirstlane((int)(blockIdx.x * 4 + (threadIdx.x >> 6)));
  const float* Srow = S_pre + (size_t)b * 128;
  const float bb2 = b2[0];
  const int kk = lane & 31;
  float vmean = 0.0f, vsd = 1.0f;
  for (int it = 0; it < 4; ++it) {
    uint32_t K0 = it == 0 ? kx.x : it == 1 ? kx.y : it == 2 ? kx.z : kx.w;
    uint32_t K1 = it == 0 ? ky.x : it == 1 ? ky.y : it == 2 ? ky.z : ky.w;
    float a[32];
    gen_eps(K0, K1, b, lane, a);
    if (it != 0) {
#pragma clang fp contract(off)
#pragma unroll
      for (int k = 0; k < 32; ++k) {
        float mk = rdlane(vmean, k);
        float sk = rdlane(vsd, k);
        a[k] = mk + sk * a[k];
      }
    }  // it==0: a = 0 + 1*eps = eps bitwise.
    float q = qeval(Srow, W1aT, b1, W2, bb2, a);
    int top[6];
    top6(q, lane, top);
    const float* Tt = T + it * 12288;
    float sel0 = Tt[(size_t)(top[0] * 32) + kk];
    if (it == 3) {
      if (lane < 32) out[(size_t)b * 32 + kk] = sel0;
    } else {
      float sel[6];
      sel[0] = sel0;
#pragma unroll
      for (int i = 1; i < 6; ++i) sel[i] = Tt[(size_t)((i * 64 + top[i]) * 32) + kk];
      stats6(sel, vmean, vsd);
    }
  }
}

// ---------------------------------------------------------------------------
extern "C" void kernel_launch(void* const* d_in, const int* in_sizes, int n_in,
                              void* d_out, int out_size, void* d_ws,
                              size_t ws_size, hipStream_t stream) {
  const float* state = (const float*)d_in[0];  // 8192*64
  const float* W1 = (const float*)d_in[1];     // 96*128
  const float* b1 = (const float*)d_in[2];     // 128
  const float* W2 = (const float*)d_in[3];     // 128
  const float* b2 = (const float*)d_in[4];     // 1
  float* out = (float*)d_out;                  // 8192*32

  float* ws = (float*)d_ws;
  float* S_pre = ws;                    // 1,048,576 floats
  float* W1aT = ws + 1048576;           // 4,096
  float* T = W1aT + 4096;               // 4 * 12,288
  float* meanW = T + 4 * 12288;         // 2,048
  float* stdW = meanW + 2048;           // 2,048  (total ~4.42 MB)

  // fold_in(key(42), it) = threefry cipher block (k=(0,42), x=(0,it))
  uint32_t K0[4], K1[4];
  for (uint32_t i = 0; i < 4; ++i) {
    uint32_t a, bb;
    tf20(0u, 42u, 0u, i, a, bb);
    K0[i] = a;
    K1[i] = bb;
  }

  k_prep_spre<<<8192, 128, 0, stream>>>(state, W1, S_pre);
  k_prep_misc<<<48, 256, 0, stream>>>(W1, W1aT, T, meanW, stdW, K0[0], K1[0]);
  for (int it = 0; it < 3; ++it)
    k_stage1<<<16, 256, 0, stream>>>(S_pre, W1aT, b1, W2, b2, T + it * 12288,
                                     T + (it + 1) * 12288, meanW, stdW, K0[it],
                                     K1[it], K0[it + 1], K1[it + 1]);
  k_main<<<2048, 256, 0, stream>>>(S_pre, W1aT, b1, W2, b2, T, out,
                                   make_uint4(K0[0], K0[1], K0[2], K0[3]),
                                   make_uint4(K1[0], K1[1], K1[2], K1[3]));
}